// Round 18
// baseline (95.581 us; speedup 1.0000x reference)
//
#include <hip/hip_runtime.h>
#include <math.h>

#define CIN   16
#define COUT  64
#define H     256
#define W     256
#define OH    254
#define OW    254
#define NTAP  9
#define HWSZ  (H * W)

typedef _Float16 f16x8  __attribute__((ext_vector_type(8)));
typedef float    f32x16 __attribute__((ext_vector_type(16)));

// weight pack: [tap 9][msub 2][lane 64][e 8] fp16; co=(l&31)+32m, cin=8*(l>>5)+e
__global__ void wpack_kernel(const float* __restrict__ w, _Float16* __restrict__ wpk) {
    int idx = blockIdx.x * 256 + threadIdx.x;   // 0..9215
    if (idx >= NTAP * 2 * 64 * 8) return;
    int e = idx & 7, l = (idx >> 3) & 63, m = (idx >> 9) & 1, t = idx >> 10;
    int co  = (l & 31) + 32 * m;
    int cin = 8 * (l >> 5) + e;
    wpk[idx] = (_Float16)w[((co * CIN + cin) * 3 + t / 3) * 3 + (t % 3)];
}

__device__ __forceinline__ float tanh_fast(float v) {
    float e = __expf(2.0f * v);
    return 1.0f - 2.0f * __builtin_amdgcn_rcpf(e + 1.0f);
}
__device__ __forceinline__ float min3f(float a, float b, float c) {
    return fminf(fminf(a, b), c);   // clang fuses to v_min3_f32
}

// 64 thr = ONE wave per block. NO LDS, NO barriers: x streams global->reg->
// cvt->MFMA B-frag directly (lane l31 = px, elem e = cin 8*g2+e). kh-frags
// rotate in registers (each input row loaded once, used for 3 output rows).
// Block = 32-px x 64-row column; grid 2048 = 8 waves/CU free-running.
__global__ __launch_bounds__(64, 2) void conv_direct_kernel(
        const float* __restrict__ x, const f16x8* __restrict__ wpk,
        const float* __restrict__ bias, float* __restrict__ out) {
    const int lane = threadIdx.x;
    const int l31  = lane & 31;
    const int g2   = lane >> 5;

    int bid = blockIdx.x;
    int nb  = (bid & 7) * 256 + (bid >> 3);   // 2048 = 8*256 bijective XCD swizzle
    const int img   = nb >> 5;
    const int col   = (nb >> 2) & 7;           // 32-px column
    const int strip = nb & 3;                  // 64-row strip
    const int P0    = col * 32;
    const int r0    = strip * 64;
    const int nr    = (strip == 3) ? 62 : 64;

    // ---- weights: 72 VGPRs, loop-invariant ----
    f16x8 wreg[NTAP][2];
#pragma unroll
    for (int t = 0; t < NTAP; ++t)
#pragma unroll
        for (int m = 0; m < 2; ++m)
            wreg[t][m] = wpk[(t * 2 + m) * 64 + lane];

    // bias C-fragment: col=l31(px), row=(q&3)+8*(q>>2)+4*g2+32m (co)
    f32x16 cbias[2];
#pragma unroll
    for (int m = 0; m < 2; ++m)
#pragma unroll
        for (int q = 0; q < 16; ++q)
            cbias[m][q] = bias[(q & 3) + 8 * (q >> 2) + 4 * g2 + 32 * m];

    // per-lane, per-cin row pointers (kw = +0/+1/+2 via imm offsets)
    int pxe = P0 + l31; if (pxe > 253) pxe = 253;   // clamp feeds only masked px
    const float* ap[8];
#pragma unroll
    for (int c = 0; c < 8; ++c)
        ap[c] = x + (size_t)img * CIN * HWSZ + (size_t)(8 * g2 + c) * HWSZ
                  + (size_t)r0 * W + pxe;

    float lv[8][3];            // in-flight loads (one input row)
    f16x8 fA[3], fB[3], fC[3]; // kh-rotating B-fragments [kw]

#define ISSUE()                                                                 \
    { _Pragma("unroll")                                                         \
      for (int c = 0; c < 8; ++c) {                                             \
          lv[c][0] = ap[c][0]; lv[c][1] = ap[c][1]; lv[c][2] = ap[c][2];        \
      } }

#define ADVANCE(nextrow)                                                        \
    { const int st_ = ((nextrow) <= 255) ? W : 0;                               \
      _Pragma("unroll")                                                         \
      for (int c = 0; c < 8; ++c) ap[c] += st_; }

#define CONSUME(FF)                                                             \
    { _Pragma("unroll")                                                         \
      for (int kw = 0; kw < 3; ++kw) {                                          \
          f16x8 q_;                                                             \
          _Pragma("unroll")                                                     \
          for (int e = 0; e < 8; ++e) q_[e] = (_Float16)lv[e][kw];              \
          FF[kw] = q_;                                                          \
      } }

    // ---- prologue: frags for rows r0, r0+1; row r0+2 loads left in flight ----
    ISSUE() ADVANCE(r0 + 1) CONSUME(fA)
    ISSUE() ADVANCE(r0 + 2) CONSUME(fB)
    ISSUE() ADVANCE(r0 + 3)

    const size_t obase = (size_t)img * OH * OW;
    const int  opx   = P0 + l31;
    const bool omask = (g2 == 0) && (opx < OW);

#define ITER(FA_, FB_, FC_, ii)                                                 \
    {                                                                           \
        CONSUME(FC_)                                                            \
        ISSUE()                                                                 \
        ADVANCE(r0 + (ii) + 4)                                                  \
        f32x16 a0, a1;                                                          \
        a0 = __builtin_amdgcn_mfma_f32_32x32x16_f16(wreg[0][0], FA_[0], cbias[0], 0, 0, 0); \
        a1 = __builtin_amdgcn_mfma_f32_32x32x16_f16(wreg[0][1], FA_[0], cbias[1], 0, 0, 0); \
        a0 = __builtin_amdgcn_mfma_f32_32x32x16_f16(wreg[1][0], FA_[1], a0, 0, 0, 0); \
        a1 = __builtin_amdgcn_mfma_f32_32x32x16_f16(wreg[1][1], FA_[1], a1, 0, 0, 0); \
        a0 = __builtin_amdgcn_mfma_f32_32x32x16_f16(wreg[2][0], FA_[2], a0, 0, 0, 0); \
        a1 = __builtin_amdgcn_mfma_f32_32x32x16_f16(wreg[2][1], FA_[2], a1, 0, 0, 0); \
        a0 = __builtin_amdgcn_mfma_f32_32x32x16_f16(wreg[3][0], FB_[0], a0, 0, 0, 0); \
        a1 = __builtin_amdgcn_mfma_f32_32x32x16_f16(wreg[3][1], FB_[0], a1, 0, 0, 0); \
        a0 = __builtin_amdgcn_mfma_f32_32x32x16_f16(wreg[4][0], FB_[1], a0, 0, 0, 0); \
        a1 = __builtin_amdgcn_mfma_f32_32x32x16_f16(wreg[4][1], FB_[1], a1, 0, 0, 0); \
        a0 = __builtin_amdgcn_mfma_f32_32x32x16_f16(wreg[5][0], FB_[2], a0, 0, 0, 0); \
        a1 = __builtin_amdgcn_mfma_f32_32x32x16_f16(wreg[5][1], FB_[2], a1, 0, 0, 0); \
        a0 = __builtin_amdgcn_mfma_f32_32x32x16_f16(wreg[6][0], FC_[0], a0, 0, 0, 0); \
        a1 = __builtin_amdgcn_mfma_f32_32x32x16_f16(wreg[6][1], FC_[0], a1, 0, 0, 0); \
        a0 = __builtin_amdgcn_mfma_f32_32x32x16_f16(wreg[7][0], FC_[1], a0, 0, 0, 0); \
        a1 = __builtin_amdgcn_mfma_f32_32x32x16_f16(wreg[7][1], FC_[1], a1, 0, 0, 0); \
        a0 = __builtin_amdgcn_mfma_f32_32x32x16_f16(wreg[8][0], FC_[2], a0, 0, 0, 0); \
        a1 = __builtin_amdgcn_mfma_f32_32x32x16_f16(wreg[8][1], FC_[2], a1, 0, 0, 0); \
        float mn = fminf(a0[0], a1[0]);                                         \
        _Pragma("unroll")                                                       \
        for (int q = 1; q < 16; ++q) mn = min3f(a0[q], a1[q], mn);              \
        mn = fminf(mn, __shfl_xor(mn, 32));                                     \
        if (omask) out[obase + (size_t)(r0 + (ii)) * OW + opx]                  \
                       = tanh_fast(tanh_fast(mn));                              \
    }

    int i = 0;
#pragma unroll 1
    for (; i + 3 <= nr; i += 3) {
        ITER(fA, fB, fC, i)
        ITER(fB, fC, fA, i + 1)
        ITER(fC, fA, fB, i + 2)
    }
    if (i < nr)     ITER(fA, fB, fC, i)
    if (i + 1 < nr) ITER(fB, fC, fA, i + 1)
}

extern "C" void kernel_launch(void* const* d_in, const int* in_sizes, int n_in,
                              void* d_out, int out_size, void* d_ws, size_t ws_size,
                              hipStream_t stream) {
    const float* x    = (const float*)d_in[0];
    const float* w    = (const float*)d_in[1];
    const float* bias = (const float*)d_in[2];
    float* out = (float*)d_out;
    _Float16* wpk = (_Float16*)d_ws;   // 9216 fp16 = 18,432 B

    wpack_kernel<<<36, 256, 0, stream>>>(w, wpk);
    conv_direct_kernel<<<2048, 64, 0, stream>>>(x, (const f16x8*)wpk, bias, out);
}

// Round 19
// 91.131 us; speedup vs baseline: 1.0488x; 1.0488x over previous
//
#include <hip/hip_runtime.h>
#include <math.h>

#define CIN   16
#define COUT  64
#define H     256
#define W     256
#define OH    254
#define OW    254
#define NTAP  9
#define HWSZ  (H * W)
#define RING  18
#define SROW  136        // f16x8 slots per ring row: 2 cin-halves * 68 px

typedef _Float16 f16x8  __attribute__((ext_vector_type(8)));
typedef float    f32x16 __attribute__((ext_vector_type(16)));

// Raw barrier WITHOUT the __syncthreads vmcnt(0) drain: global loads stay in
// flight across it (T3/T4). lgkmcnt(0) orders our ds_writes for other waves.
#define BARRIER()                                                               \
    __builtin_amdgcn_sched_barrier(0);                                          \
    asm volatile("s_waitcnt lgkmcnt(0)" ::: "memory");                          \
    __builtin_amdgcn_s_barrier();                                               \
    __builtin_amdgcn_sched_barrier(0);

// weight pack: [tap 9][msub 2][lane 64][e 8] fp16; co=(l&31)+32m, cin=8*(l>>5)+e
__global__ void wpack_kernel(const float* __restrict__ w, _Float16* __restrict__ wpk) {
    int idx = blockIdx.x * 256 + threadIdx.x;   // 0..9215
    if (idx >= NTAP * 2 * 64 * 8) return;
    int e = idx & 7, l = (idx >> 3) & 63, m = (idx >> 9) & 1, t = idx >> 10;
    int co  = (l & 31) + 32 * m;
    int cin = 8 * (l >> 5) + e;
    wpk[idx] = (_Float16)w[((co * CIN + cin) * 3 + t / 3) * 3 + (t % 3)];
}

__device__ __forceinline__ float tanh_fast(float v) {
    float e = __expf(2.0f * v);
    return 1.0f - 2.0f * __builtin_amdgcn_rcpf(e + 1.0f);
}
__device__ __forceinline__ float min3f(float a, float b, float c) {
    return fminf(fminf(a, b), c);   // clang fuses to v_min3_f32
}

// 256 thr = 4 waves (2 px-slices x 2 row-groups, full 64-cout per wave).
// Persistent block = (img, 64px col, 128-row half); 16 tiles of 8 out-rows.
// 18-row LDS ring; raw barriers (no vmem drain) let next-tile loads stream
// under this tile's MFMA phase -> stage/compute overlap per CU.
__global__ __launch_bounds__(256, 2) void conv_mfma_kernel(
        const float* __restrict__ x, const f16x8* __restrict__ wpk,
        const float* __restrict__ bias, float* __restrict__ out) {
    __shared__ f16x8 ring[RING * SROW];    // 39,168 B
    __shared__ float bias_lds[64];         // [g2][m][q] pre-arranged

    const int tid  = threadIdx.x;
    const int lane = tid & 63;

    int bid = blockIdx.x;
    int nb  = (bid & 7) * 64 + (bid >> 3);     // 512 = 8*64 bijective XCD swizzle
    const int img  = nb >> 3;
    const int rem  = nb & 7;
    const int colb = rem & 3;                  // 64-px column
    const int half = rem >> 2;                 // 128-row half
    const int base = 64 * colb;
    const int R0   = 128 * half;
    const int S0   = half ? 2 : 0;             // R0 % 18

    const float* xb = x + (size_t)img * CIN * HWSZ;

    // ---- weights: full 64 cout -> 72 VGPRs ----
    f16x8 wreg[NTAP][2];
#pragma unroll
    for (int t = 0; t < NTAP; ++t)
#pragma unroll
        for (int m = 0; m < 2; ++m)
            wreg[t][m] = wpk[(t * 2 + m) * 64 + lane];

    // bias -> LDS in lane layout: bias_lds[g2*32+m*16+q] = bias[(q&3)+8*(q>>2)+4*g2+32*m]
    if (tid < 64) {
        int q = tid & 15, m = (tid >> 4) & 1, g = tid >> 5;
        bias_lds[tid] = bias[(q & 3) + 8 * (q >> 2) + 4 * g + 32 * m];
    }

    // ---- staging unit decode: u = tid + 256k over [row8 0..7][r2 0..67] ----
    int r8[3], gq[3], gx[3], wof[3];
#pragma unroll
    for (int k = 0; k < 3; ++k) {
        int u  = tid + 256 * k;
        r8[k]  = u / 68;
        int r2 = u - 68 * r8[k];
        int g  = (r2 >= 34) ? 1 : 0;
        int p  = r2 - 34 * g;
        int px = base + 2 * p; if (px > 254) px = 254;
        gq[k]  = g;
        gx[k]  = px;
        wof[k] = g * 68 + 2 * p;
    }
    const bool act2 = (tid < 32);              // 544 - 512 units

    float2 vA[8], vB[8], vC[8];

#define PLOADK(k, rowAbs, vv)                                                   \
    {                                                                           \
        int gr = (rowAbs); if (gr > 255) gr = 255;                              \
        const float* gp = xb + (size_t)(8 * gq[k]) * HWSZ + (size_t)gr * W + gx[k]; \
        _Pragma("unroll")                                                       \
        for (int cc = 0; cc < 8; ++cc) vv[cc] = *(const float2*)(gp + (size_t)cc * HWSZ); \
    }

#define PWRITEK(k, slot, vv)                                                    \
    {                                                                           \
        f16x8 q0, q1;                                                           \
        _Pragma("unroll")                                                       \
        for (int cc = 0; cc < 8; ++cc) { q0[cc] = (_Float16)vv[cc].x;           \
                                         q1[cc] = (_Float16)vv[cc].y; }         \
        const int ad = (slot) * SROW + wof[k];                                  \
        ring[ad]     = q0;                                                      \
        ring[ad + 1] = q1;                                                      \
    }

    // ---- prologue: stage rows R0..R0+9 (680 units over 3 rounds) ----
#pragma unroll
    for (int k = 0; k < 3; ++k) {
        int u = tid + 256 * k;
        if (k == 2 && tid >= 168) break;
        int r10 = u / 68;
        int r2  = u - 68 * r10;
        int g   = (r2 >= 34) ? 1 : 0;
        int p   = r2 - 34 * g;
        int px  = base + 2 * p; if (px > 254) px = 254;
        const float* gp = xb + (size_t)(8 * g) * HWSZ + (size_t)(R0 + r10) * W + px;
        float2 vm[8];
#pragma unroll
        for (int cc = 0; cc < 8; ++cc) vm[cc] = *(const float2*)(gp + (size_t)cc * HWSZ);
        f16x8 q0, q1;
#pragma unroll
        for (int cc = 0; cc < 8; ++cc) { q0[cc] = (_Float16)vm[cc].x;
                                         q1[cc] = (_Float16)vm[cc].y; }
        const int ad = (S0 + r10) * SROW + g * 68 + 2 * p;
        ring[ad]     = q0;
        ring[ad + 1] = q1;
    }

    // initial prefetch: rows R0+10+r8 (PWRITten at tile 0)
    PLOADK(0, R0 + 10 + r8[0], vA)
    PLOADK(1, R0 + 10 + r8[1], vB)
    if (act2) PLOADK(2, R0 + 10 + r8[2], vC)
    BARRIER()

    const int wv  = tid >> 6;
    const int s   = wv & 1;                    // 32-px slice
    const int rg  = wv >> 1;                   // 4-row group
    const int l31 = lane & 31;
    const int g2  = lane >> 5;
    const int foff = g2 * 68 + 32 * s + l31;
    const int opx  = base + 32 * s + l31;
    const size_t obase = (size_t)img * OH * OW;
    const f32x16* bp = (const f32x16*)(bias_lds + g2 * 32);

    int slot0 = S0;

#pragma unroll 1
    for (int t = 0; t < 16; ++t) {
        const int row0 = R0 + 8 * t;

        // ---- compute: 2 chunks x 2 rows (reads ring rows 8t..8t+9) ----
#pragma unroll
        for (int c = 0; c < 2; ++c) {
            const int rowoff = 4 * rg + 2 * c;
            f32x16 cb0 = bp[0], cb1 = bp[1];   // C-operands from LDS
            f32x16 acc[2][2];
#pragma unroll
            for (int dd = 0; dd < 4; ++dd) {
                int sl = slot0 + rowoff + dd; if (sl >= RING) sl -= RING;
                const f16x8* rp = ring + sl * SROW + foff;
                f16x8 f0 = rp[0], f1 = rp[1], f2 = rp[2];
#pragma unroll
                for (int kw = 0; kw < 3; ++kw) {
                    f16x8 ff = (kw == 0) ? f0 : (kw == 1) ? f1 : f2;
#pragma unroll
                    for (int ro = 0; ro < 2; ++ro) {
                        const int kh = dd - ro;
                        if (kh < 0 || kh > 2) continue;
#pragma unroll
                        for (int m = 0; m < 2; ++m) {
                            const f32x16& cin_ = (kh == 0 && kw == 0)
                                               ? (m == 0 ? cb0 : cb1) : acc[ro][m];
                            acc[ro][m] = __builtin_amdgcn_mfma_f32_32x32x16_f16(
                                wreg[kh * 3 + kw][m], ff, cin_, 0, 0, 0);
                        }
                    }
                }
            }
            // epilogue: min over 64 cout -> tanh(tanh) -> store
#pragma unroll
            for (int ro = 0; ro < 2; ++ro) {
                float mn = fminf(acc[ro][0][0], acc[ro][1][0]);
#pragma unroll
                for (int q = 1; q < 16; ++q)
                    mn = min3f(acc[ro][0][q], acc[ro][1][q], mn);
                mn = fminf(mn, __shfl_xor(mn, 32));
                float t2 = tanh_fast(tanh_fast(mn));
                const int oh = row0 + rowoff + ro;
                if (g2 == 0 && oh < OH && opx < OW)
                    out[obase + (size_t)oh * OW + opx] = t2;
            }
        }

        // ---- stage: write rows 8t+10..17 (compiler emits counted vmcnt here) ----
        if (t <= 14) {
            int sl0 = slot0 + 10 + r8[0]; if (sl0 >= RING) sl0 -= RING;
            int sl1 = slot0 + 10 + r8[1]; if (sl1 >= RING) sl1 -= RING;
            PWRITEK(0, sl0, vA)
            PWRITEK(1, sl1, vB)
            if (act2) {
                int sl2 = slot0 + 10 + r8[2]; if (sl2 >= RING) sl2 -= RING;
                PWRITEK(2, sl2, vC)
            }
        }
        // ---- issue loads for rows 8t+18..25 (stream across the barrier) ----
        if (t <= 13) {
            PLOADK(0, row0 + 18 + r8[0], vA)
            PLOADK(1, row0 + 18 + r8[1], vB)
            if (act2) PLOADK(2, row0 + 18 + r8[2], vC)
        }
        BARRIER()
        slot0 += 8; if (slot0 >= RING) slot0 -= RING;
    }
}

extern "C" void kernel_launch(void* const* d_in, const int* in_sizes, int n_in,
                              void* d_out, int out_size, void* d_ws, size_t ws_size,
                              hipStream_t stream) {
    const float* x    = (const float*)d_in[0];
    const float* w    = (const float*)d_in[1];
    const float* bias = (const float*)d_in[2];
    float* out = (float*)d_out;
    _Float16* wpk = (_Float16*)d_ws;   // 9216 fp16 = 18,432 B

    wpack_kernel<<<36, 256, 0, stream>>>(w, wpk);
    conv_mfma_kernel<<<512, 256, 0, stream>>>(x, (const f16x8*)wpk, bias, out);
}